// Round 2
// baseline (247.339 us; speedup 1.0000x reference)
//
#include <hip/hip_runtime.h>

// Circle (ball) projection: out = center + (x-center) * min(1, R/max(||x-center||,1e-12))
// B = 8,388,608 points, 3 fp32 coords, AoS [B,3].
//
// R3 = R2 structure + the missing compiler fences.
//
// R2 post-mortem: wave-private no-barrier LDS transpose failed (absmax 6.47)
// because the COMPILER's memory model is per-thread. Lane l's transposed read
// wx[l+64] vs lane l's own write wx[3l+1]: address diff 2l-63 is always odd,
// so BasicAA proves per-thread NoAlias and the scheduler may hoist the ds_read
// above the ds_write. The real dependency is CROSS-LANE (lane 0 reads lane
// 21's write) — invisible to single-thread alias analysis. Hardware DS ops
// from one wave ARE processed in order; what's needed is only a COMPILER
// ordering fence at each LDS write->read boundary:
//     asm volatile("s_waitcnt lgkmcnt(0)" ::: "memory")
// This emits no s_barrier and does NOT drain vmcnt -> the 6 prefetched global
// loads stay in flight across the fence (unlike __syncthreads, whose
// vmcnt(0)+lgkmcnt(0) drain was R1's convoy).
//
// Structure (unchanged from R2):
//  - Wave-private LDS slices (4 waves x 192 float4 x 2 arrays = 24 KiB/block),
//    no __syncthreads anywhere.
//  - Persistent grid: 1024 blocks (4/CU, 96 KiB LDS/CU, all co-resident),
//    8 chunks per wave, 1-deep register prefetch: chunk t+1's 6 global loads
//    are in flight under chunk t's stage/compute/store.
//  - Non-temporal stores: the 100 MB output stream doesn't evict the 201 MB
//    (L3-resident) inputs from the 256 MiB Infinity Cache.
//  - rsqrtf scale: min(1, R*rsqrt(max(n2,1e-24))) == min(1, R/max(n,1e-12)).
//
// Chunk = 256 points = 192 float4 per array per wave. nf4 = 6,291,456
// -> nchunks = 32768 = 1024 blocks * 4 waves * 8 iterations exactly.

#define RADIUS 1.0f

typedef float f32x4 __attribute__((ext_vector_type(4)));

// Compiler memory-ordering fence for cross-lane LDS dataflow within a wave.
// "memory" clobber: no memory op may be moved across (fixes the per-thread
// NoAlias reordering). lgkmcnt(0): ds_writes complete before ds_reads issue.
// No s_barrier, no vmcnt drain.
#define WAVE_LDS_FENCE() asm volatile("s_waitcnt lgkmcnt(0)" ::: "memory")

__global__ __launch_bounds__(256, 4) void circle_proj_wave(
    const float4* __restrict__ xv,
    const float4* __restrict__ cv,
    float4* __restrict__ ov,
    long nchunks)
{
    // Wave-private staging: 4 waves x (192 x + 192 c) float4 = 24 KiB/block.
    __shared__ float4 sx[4][192];
    __shared__ float4 sc[4][192];

    const int wid  = threadIdx.x >> 6;
    const int lane = threadIdx.x & 63;
    float4* wx = sx[wid];
    float4* wc = sc[wid];

    const long nw = (long)gridDim.x * 4;      // total waves
    long ch = (long)blockIdx.x * 4 + wid;     // this wave's first chunk
    if (ch >= nchunks) return;

    // Prologue: issue loads for the first chunk.
    long b = ch * 192 + lane;
    float4 r0 = xv[b], r1 = xv[b + 64], r2 = xv[b + 128];
    float4 s0 = cv[b], s1 = cv[b + 64], s2 = cv[b + 128];

    while (true) {
        const long chn  = ch + nw;
        const bool more = (chn < nchunks);    // wave-uniform branch

        // Prefetch next chunk's 6 float4 loads -> in flight under this
        // chunk's LDS transpose + compute + stores (vmcnt not drained by
        // the fences below).
        float4 t0, t1, t2, u0, u1, u2;
        if (more) {
            const long bn = chn * 192 + lane;
            t0 = xv[bn]; t1 = xv[bn + 64]; t2 = xv[bn + 128];
            u0 = cv[bn]; u1 = cv[bn + 64]; u2 = cv[bn + 128];
        }

        // Stage current chunk into wave-private LDS (coalesced layout).
        wx[lane] = r0; wx[lane + 64] = r1; wx[lane + 128] = r2;
        wc[lane] = s0; wc[lane + 64] = s1; wc[lane + 128] = s2;

        WAVE_LDS_FENCE();   // cross-lane write->read boundary #1

        // Transposed read: lane l pulls its 4 points (12 consecutive floats).
        // float4-index stride 3 distributes over all bank groups (gcd(3,8)=1)
        // -> measured conflict-free in R1.
        const float4 x0 = wx[3*lane + 0], x1 = wx[3*lane + 1], x2 = wx[3*lane + 2];
        const float4 c0 = wc[3*lane + 0], c1 = wc[3*lane + 1], c2 = wc[3*lane + 2];

        const float px[12] = {x0.x, x0.y, x0.z, x0.w, x1.x, x1.y, x1.z, x1.w, x2.x, x2.y, x2.z, x2.w};
        const float pc[12] = {c0.x, c0.y, c0.z, c0.w, c1.x, c1.y, c1.z, c1.w, c2.x, c2.y, c2.z, c2.w};
        float po[12];

#pragma unroll
        for (int p = 0; p < 4; ++p) {
            const float dx = px[3*p + 0] - pc[3*p + 0];
            const float dy = px[3*p + 1] - pc[3*p + 1];
            const float dz = px[3*p + 2] - pc[3*p + 2];
            const float n2 = dx*dx + dy*dy + dz*dz;
            // min(1, R/max(n,1e-12)) == min(1, R*rsqrt(max(n2,1e-24)))
            const float scale = fminf(1.0f, RADIUS * rsqrtf(fmaxf(n2, 1e-24f)));
            po[3*p + 0] = pc[3*p + 0] + dx * scale;
            po[3*p + 1] = pc[3*p + 1] + dy * scale;
            po[3*p + 2] = pc[3*p + 2] + dz * scale;
        }

        // Results back through wave-private LDS (reuse wx), then coalesced
        // non-temporal stores.
        wx[3*lane + 0] = make_float4(po[0], po[1], po[2],  po[3]);
        wx[3*lane + 1] = make_float4(po[4], po[5], po[6],  po[7]);
        wx[3*lane + 2] = make_float4(po[8], po[9], po[10], po[11]);

        WAVE_LDS_FENCE();   // cross-lane write->read boundary #2

        const float4 o0 = wx[lane], o1 = wx[lane + 64], o2 = wx[lane + 128];
        const long ob = ch * 192 + lane;
        {
            const f32x4 v0 = {o0.x, o0.y, o0.z, o0.w};
            const f32x4 v1 = {o1.x, o1.y, o1.z, o1.w};
            const f32x4 v2 = {o2.x, o2.y, o2.z, o2.w};
            __builtin_nontemporal_store(v0, (f32x4*)&ov[ob]);
            __builtin_nontemporal_store(v1, (f32x4*)&ov[ob + 64]);
            __builtin_nontemporal_store(v2, (f32x4*)&ov[ob + 128]);
        }

        if (!more) break;
        r0 = t0; r1 = t1; r2 = t2;
        s0 = u0; s1 = u1; s2 = u2;
        ch = chn;
    }
}

// Safety tail: one thread per point, scalar loads (only launched if the
// element count isn't a multiple of the 256-point chunk — not hit at B=8M).
__global__ __launch_bounds__(256) void circle_proj_tail(
    const float* __restrict__ x,
    const float* __restrict__ c,
    float* __restrict__ o,
    long start_pt, long npts)
{
    long p = start_pt + blockIdx.x * blockDim.x + threadIdx.x;
    if (p >= npts) return;
    float dx = x[3*p+0] - c[3*p+0];
    float dy = x[3*p+1] - c[3*p+1];
    float dz = x[3*p+2] - c[3*p+2];
    float n = sqrtf(dx*dx + dy*dy + dz*dz);
    float scale = fminf(1.0f, RADIUS / fmaxf(n, 1e-12f));
    o[3*p+0] = c[3*p+0] + dx * scale;
    o[3*p+1] = c[3*p+1] + dy * scale;
    o[3*p+2] = c[3*p+2] + dz * scale;
}

extern "C" void kernel_launch(void* const* d_in, const int* in_sizes, int n_in,
                              void* d_out, int out_size, void* d_ws, size_t ws_size,
                              hipStream_t stream) {
    const float* x = (const float*)d_in[0];   // [B,3] fp32
    const float* c = (const float*)d_in[1];   // [B,3] fp32
    float* out = (float*)d_out;

    long total_floats = in_sizes[0];          // B*3 = 25,165,824
    long nf4 = total_floats / 4;              // 6,291,456
    long nchunks = nf4 / 192;                 // 32,768 (exact at this size)

    if (nchunks > 0) {
        long blocks = (nchunks + 3) / 4;
        if (blocks > 1024) blocks = 1024;     // persistent: 4 blocks/CU, all resident
        circle_proj_wave<<<(int)blocks, 256, 0, stream>>>(
            (const float4*)x, (const float4*)c, (float4*)out, nchunks);
    }

    long pts_done = nchunks * 256;
    long npts = total_floats / 3;
    if (pts_done < npts) {
        long rem = npts - pts_done;
        int grid = (int)((rem + 255) / 256);
        circle_proj_tail<<<grid, 256, 0, stream>>>(x, c, out, pts_done, npts);
    }
}

// Round 3
// 246.898 us; speedup vs baseline: 1.0018x; 1.0018x over previous
//
#include <hip/hip_runtime.h>

// Circle (ball) projection: out = center + (x-center) * min(1, R/max(||x-center||,1e-12))
// B = 8,388,608 points, 3 fp32 coords, AoS [B,3].
//
// R4: pure streaming, NO LDS, NO transpose — structural clone of the 6.3 TB/s
// float4 copy microbenchmark.
//
// R3 post-mortem: three different structures (naive stride-3, LDS+barriers,
// wave-private pipelined LDS) all plateau at ~3.1 TB/s; profiler replays with
// warm L3 (reads fully cached, only writes to HBM) run at the SAME duration.
// => wall is not HBM BW, not barrier convoy, not prefetch depth. Common
// factor: the per-wave LDS round-trip chain (18 serialized b128 DS ops/iter)
// at <=50% occupancy. The known-good 6.29 TB/s copy has no LDS, no per-wave
// dependency chain, 100% occupancy. This kernel replicates that shape.
//
// Key trick — register-resident AoS handling:
//   A chunk of 63 float4 = 252 floats = 84 points EXACTLY (63*4 % 3 == 0),
//   so chunks are point-aligned and lane l's float4 has phase = l % 3:
//     phase 0: [p.x p.y p.z q.x]   head point local,  tail partial = d3^2
//     phase 1: [p.y p.z q.x q.y]   head part d0+d1,   tail part d2+d3
//     phase 2: [p.z q.x q.y q.z]   head part d0,      tail point local
//   A split point only ever spans lanes l, l+1 of the SAME wave; its |d|^2
//   needs one cross-lane add: __shfl_up(tail_partial) + __shfl_down(head_
//   partial). Two shuffles replace the whole LDS transpose. Lane 63 idles
//   (63-lane chunks): 1.6% lane waste, zero duplicate traffic.
//
//   No LDS => occupancy capped only by VGPRs (~40) => 32 waves/CU possible.
//   Grid: 2048 blocks (8 blocks/CU, 100% occupancy), grid-stride loop.
//   Plain stores (R3 showed nontemporal stores were -6% and didn't cut FETCH).

#define RADIUS 1.0f

__global__ __launch_bounds__(256, 8) void circle_proj_stream(
    const float4* __restrict__ xv,
    const float4* __restrict__ cv,
    float4* __restrict__ ov,
    long nchunks)   // number of 63-float4 (84-point) chunks
{
    const int wid   = threadIdx.x >> 6;
    const int lane  = threadIdx.x & 63;
    const int phase = lane % 3;            // f4 index mod 3 (63 ≡ 0 mod 3)
    const bool ph0  = (phase == 0);
    const bool ph2  = (phase == 2);
    const bool b1   = (phase < 2);         // comp1 belongs to head point

    const long nw = (long)gridDim.x * 4;   // total waves
    const bool active = (lane < 63);

    for (long ch = (long)blockIdx.x * 4 + wid; ch < nchunks; ch += nw) {
        const long f = ch * 63 + lane;

        float4 x4 = make_float4(0.f, 0.f, 0.f, 0.f);
        float4 c4 = make_float4(0.f, 0.f, 0.f, 0.f);
        if (active) { x4 = xv[f]; c4 = cv[f]; }

        const float d0 = x4.x - c4.x, d1 = x4.y - c4.y;
        const float d2 = x4.z - c4.z, d3 = x4.w - c4.w;
        const float q0 = d0*d0, q1 = d1*d1, q2 = d2*d2, q3 = d3*d3;

        // Own-floats contribution to this lane's head point / tail point.
        const float hp = q0 + (b1  ? q1 : 0.0f) + (ph0 ? q2 : 0.0f);
        const float tp = q3 + (!ph0 ? q2 : 0.0f) + (ph2 ? q1 : 0.0f);

        // Cross-lane completion of split points (neighbor lanes only).
        const float hp_next = __shfl_down(hp, 1, 64);  // from lane l+1
        const float tp_prev = __shfl_up(tp, 1, 64);    // from lane l-1

        const float n2h = hp + (ph0 ? 0.0f : tp_prev); // full |d|^2, head pt
        const float n2t = tp + (ph2 ? 0.0f : hp_next); // full |d|^2, tail pt

        // min(1, R/max(n,1e-12)) == min(1, R*rsqrt(max(n2,1e-24)))
        const float sh = fminf(1.0f, RADIUS * rsqrtf(fmaxf(n2h, 1e-24f)));
        const float st = fminf(1.0f, RADIUS * rsqrtf(fmaxf(n2t, 1e-24f)));

        // Component -> point mapping: comp0 always head, comp3 always tail,
        // comp1 head iff phase<2, comp2 head iff phase==0.
        const float s0 = sh;
        const float s1 = b1  ? sh : st;
        const float s2 = ph0 ? sh : st;
        const float s3 = st;

        if (active) {
            ov[f] = make_float4(c4.x + d0*s0, c4.y + d1*s1,
                                c4.z + d2*s2, c4.w + d3*s3);
        }
    }
}

// Tail: one thread per point, scalar loads. Covers the last (nf4 % 63) float4s
// at point granularity (32 points at B=8M).
__global__ __launch_bounds__(256) void circle_proj_tail(
    const float* __restrict__ x,
    const float* __restrict__ c,
    float* __restrict__ o,
    long start_pt, long npts)
{
    long p = start_pt + blockIdx.x * blockDim.x + threadIdx.x;
    if (p >= npts) return;
    float dx = x[3*p+0] - c[3*p+0];
    float dy = x[3*p+1] - c[3*p+1];
    float dz = x[3*p+2] - c[3*p+2];
    float n = sqrtf(dx*dx + dy*dy + dz*dz);
    float scale = fminf(1.0f, RADIUS / fmaxf(n, 1e-12f));
    o[3*p+0] = c[3*p+0] + dx * scale;
    o[3*p+1] = c[3*p+1] + dy * scale;
    o[3*p+2] = c[3*p+2] + dz * scale;
}

extern "C" void kernel_launch(void* const* d_in, const int* in_sizes, int n_in,
                              void* d_out, int out_size, void* d_ws, size_t ws_size,
                              hipStream_t stream) {
    const float* x = (const float*)d_in[0];   // [B,3] fp32
    const float* c = (const float*)d_in[1];   // [B,3] fp32
    float* out = (float*)d_out;

    long total_floats = in_sizes[0];          // B*3 = 25,165,824
    long nf4 = total_floats / 4;              // 6,291,456
    long nchunks = nf4 / 63;                  // 99,864 chunks of 84 points

    if (nchunks > 0) {
        long blocks = (nchunks + 3) / 4;
        if (blocks > 2048) blocks = 2048;     // 8 blocks/CU -> 32 waves/CU (100%)
        circle_proj_stream<<<(int)blocks, 256, 0, stream>>>(
            (const float4*)x, (const float4*)c, (float4*)out, nchunks);
    }

    long pts_done = nchunks * 84;             // chunks are point-aligned
    long npts = total_floats / 3;
    if (pts_done < npts) {
        long rem = npts - pts_done;
        int grid = (int)((rem + 255) / 256);
        circle_proj_tail<<<grid, 256, 0, stream>>>(x, c, out, pts_done, npts);
    }
}